// Round 1
// baseline (16073.622 us; speedup 1.0000x reference)
//
#include <hip/hip_runtime.h>
#include <math.h>

#define Bn 4
#define Sn 2048
#define Dn 1024
#define Hn 16
#define DHn 64
#define QT 128   // query rows per block
#define KT 64    // keys per tile
#define LSTR 68  // LDS row stride in floats (64 + 4 pad)

// XOR swizzle on the float4-column index so the 8 per-lane K-row reads in the
// score loop land in 8 distinct bank groups (row stride 68*4B => 8*stride == 0 mod 32 banks).
__device__ __forceinline__ int pc4(int row, int c4) { return c4 ^ ((row >> 3) & 7); }

__device__ __forceinline__ float4 f4mul(float4 a, float4 b) {
    return make_float4(a.x * b.x, a.y * b.y, a.z * b.z, a.w * b.w);
}

__global__ __launch_bounds__(256, 2)
void attn_kernel(const float* __restrict__ qin, const int* __restrict__ masks,
                 const float* __restrict__ pQ, const float* __restrict__ pK,
                 const float* __restrict__ pV, float* __restrict__ out)
{
    __shared__ __attribute__((aligned(16))) float Qs[QT * LSTR];
    __shared__ __attribute__((aligned(16))) float Ks[KT * LSTR];
    __shared__ __attribute__((aligned(16))) float Vs[KT * LSTR];

    const int n  = blockIdx.y;      // b*H + h
    const int b  = n >> 4;
    const int h  = n & 15;
    const int mb = n & 3;           // == n % B (mask tiling bug preserved)
    const int q0 = blockIdx.x * QT;

    const int t    = threadIdx.x;   // 0..255
    const int tx   = t & 7;         // key/dh split within row-group
    const int ty   = t >> 3;        // 0..31 row group (4 q-rows each)
    const int lane = t & 63;

    const float* xbase = qin + (size_t)b * Sn * Dn + h * DHn;

    // ---- load Q tile, scaled by proj_Q ----
    #pragma unroll
    for (int i = 0; i < (QT * DHn / 4) / 256; ++i) {   // 8 iterations
        int f4  = t + i * 256;
        int row = f4 >> 4;          // 16 float4 per row
        int c4  = f4 & 15;
        float4 val = *(const float4*)(xbase + (size_t)(q0 + row) * Dn + c4 * 4);
        float4 p   = *(const float4*)(pQ + h * DHn + c4 * 4);
        *(float4*)&Qs[row * LSTR + pc4(row, c4) * 4] = f4mul(val, p);
    }

    float m_[4], l_[4];
    float4 c0[4], c1[4];
    #pragma unroll
    for (int qq = 0; qq < 4; ++qq) {
        m_[qq] = -1e30f; l_[qq] = 0.f;
        c0[qq] = make_float4(0.f, 0.f, 0.f, 0.f);
        c1[qq] = make_float4(0.f, 0.f, 0.f, 0.f);
    }

    for (int kt = 0; kt < Sn / KT; ++kt) {
        __syncthreads();   // covers initial Qs load and prior-tile K/V use
        // ---- stage K,V tiles (x scaled by proj_K / proj_V) ----
        #pragma unroll
        for (int i = 0; i < (KT * DHn / 4) / 256; ++i) {   // 4 iterations
            int f4  = t + i * 256;
            int row = f4 >> 4;
            int c4  = f4 & 15;
            float4 val = *(const float4*)(xbase + (size_t)(kt * KT + row) * Dn + c4 * 4);
            float4 pk  = *(const float4*)(pK + h * DHn + c4 * 4);
            float4 pv  = *(const float4*)(pV + h * DHn + c4 * 4);
            int off = row * LSTR + pc4(row, c4) * 4;
            *(float4*)&Ks[off] = f4mul(val, pk);
            *(float4*)&Vs[off] = f4mul(val, pv);
        }
        __syncthreads();

        // ---- scores: s_[qq][j] = Qrow(ty*4+qq) . Krow(tx*8+j) ----
        float s_[4][8];
        #pragma unroll
        for (int qq = 0; qq < 4; ++qq)
            #pragma unroll
            for (int j = 0; j < 8; ++j) s_[qq][j] = 0.f;

        #pragma unroll
        for (int d4 = 0; d4 < 16; ++d4) {
            float4 kv[8];
            #pragma unroll
            for (int j = 0; j < 8; ++j) {
                int kr = tx * 8 + j;
                kv[j] = *(const float4*)&Ks[kr * LSTR + pc4(kr, d4) * 4];
            }
            #pragma unroll
            for (int qq = 0; qq < 4; ++qq) {
                int qr = ty * 4 + qq;
                float4 qv = *(const float4*)&Qs[qr * LSTR + pc4(qr, d4) * 4];
                #pragma unroll
                for (int j = 0; j < 8; ++j) {
                    s_[qq][j] += qv.x * kv[j].x + qv.y * kv[j].y
                               + qv.z * kv[j].z + qv.w * kv[j].w;
                }
            }
        }

        // ---- scale + mask (masked -> -1e-10, preserved from source) ----
        const int* mptr = masks + ((size_t)mb * Sn + (q0 + ty * 4)) * Sn + kt * KT + tx * 8;
        #pragma unroll
        for (int qq = 0; qq < 4; ++qq) {
            int4 ma = *(const int4*)(mptr + (size_t)qq * Sn);
            int4 mc = *(const int4*)(mptr + (size_t)qq * Sn + 4);
            const float sc = 0.03125f;   // 1/sqrt(1024)
            s_[qq][0] = ma.x ? -1e-10f : s_[qq][0] * sc;
            s_[qq][1] = ma.y ? -1e-10f : s_[qq][1] * sc;
            s_[qq][2] = ma.z ? -1e-10f : s_[qq][2] * sc;
            s_[qq][3] = ma.w ? -1e-10f : s_[qq][3] * sc;
            s_[qq][4] = mc.x ? -1e-10f : s_[qq][4] * sc;
            s_[qq][5] = mc.y ? -1e-10f : s_[qq][5] * sc;
            s_[qq][6] = mc.z ? -1e-10f : s_[qq][6] * sc;
            s_[qq][7] = mc.w ? -1e-10f : s_[qq][7] * sc;
        }

        // ---- online softmax (8 tx lanes per row cooperate) ----
        #pragma unroll
        for (int qq = 0; qq < 4; ++qq) {
            float tmax = s_[qq][0];
            #pragma unroll
            for (int j = 1; j < 8; ++j) tmax = fmaxf(tmax, s_[qq][j]);
            tmax = fmaxf(tmax, __shfl_xor(tmax, 1, 64));
            tmax = fmaxf(tmax, __shfl_xor(tmax, 2, 64));
            tmax = fmaxf(tmax, __shfl_xor(tmax, 4, 64));
            float mnew  = fmaxf(m_[qq], tmax);
            float alpha = __expf(m_[qq] - mnew);
            float ps = 0.f;
            #pragma unroll
            for (int j = 0; j < 8; ++j) {
                float e = __expf(s_[qq][j] - mnew);
                s_[qq][j] = e;
                ps += e;
            }
            ps += __shfl_xor(ps, 1, 64);
            ps += __shfl_xor(ps, 2, 64);
            ps += __shfl_xor(ps, 4, 64);
            l_[qq] = l_[qq] * alpha + ps;
            m_[qq] = mnew;
            c0[qq].x *= alpha; c0[qq].y *= alpha; c0[qq].z *= alpha; c0[qq].w *= alpha;
            c1[qq].x *= alpha; c1[qq].y *= alpha; c1[qq].z *= alpha; c1[qq].w *= alpha;
        }

        // ---- PV: ctx[qq][tx*8 .. tx*8+7] += p_k * V[k][...] ----
        #pragma unroll
        for (int j = 0; j < 8; ++j) {
            #pragma unroll
            for (int g = 0; g < 8; ++g) {
                int k = g * 8 + j;             // key owned by lane-group g, slot j
                float4 v0 = *(const float4*)&Vs[k * LSTR + pc4(k, tx * 2) * 4];
                float4 v1 = *(const float4*)&Vs[k * LSTR + pc4(k, tx * 2 + 1) * 4];
                int src = (lane & 56) | g;
                #pragma unroll
                for (int qq = 0; qq < 4; ++qq) {
                    float pk = __shfl(s_[qq][j], src, 64);
                    c0[qq].x += pk * v0.x; c0[qq].y += pk * v0.y;
                    c0[qq].z += pk * v0.z; c0[qq].w += pk * v0.w;
                    c1[qq].x += pk * v1.x; c1[qq].y += pk * v1.y;
                    c1[qq].z += pk * v1.z; c1[qq].w += pk * v1.w;
                }
            }
        }
    }

    // ---- epilogue: ctx / l  -> d_out (raw context; LN kernel finishes) ----
    #pragma unroll
    for (int qq = 0; qq < 4; ++qq) {
        float inv = 1.f / l_[qq];
        float4 o0 = make_float4(c0[qq].x * inv, c0[qq].y * inv, c0[qq].z * inv, c0[qq].w * inv);
        float4 o1 = make_float4(c1[qq].x * inv, c1[qq].y * inv, c1[qq].z * inv, c1[qq].w * inv);
        float* obase = out + ((size_t)b * Sn + (q0 + ty * 4 + qq)) * Dn + h * DHn + tx * 8;
        *(float4*)obase       = o0;
        *(float4*)(obase + 4) = o1;
    }
}

// residual + LayerNorm, in-place on d_out (reads ctx from out, adds q, normalizes)
__global__ __launch_bounds__(256)
void ln_kernel(const float* __restrict__ qin, const float* __restrict__ gamma,
               const float* __restrict__ beta, float* __restrict__ out)
{
    const int row = blockIdx.x;       // b*S + s
    const int t   = threadIdx.x;      // 256 threads, one float4 each (D=1024)
    const size_t base = (size_t)row * Dn + t * 4;

    float4 c = *(const float4*)(out + base);
    float4 r = *(const float4*)(qin + base);
    float4 v = make_float4(c.x + r.x, c.y + r.y, c.z + r.z, c.w + r.w);

    float sum = v.x + v.y + v.z + v.w;
    float sq  = v.x * v.x + v.y * v.y + v.z * v.z + v.w * v.w;
    #pragma unroll
    for (int off = 32; off >= 1; off >>= 1) {
        sum += __shfl_xor(sum, off, 64);
        sq  += __shfl_xor(sq,  off, 64);
    }
    __shared__ float as_[4], aq_[4];
    const int wid = t >> 6, ln = t & 63;
    if (ln == 0) { as_[wid] = sum; aq_[wid] = sq; }
    __syncthreads();
    sum = as_[0] + as_[1] + as_[2] + as_[3];
    sq  = aq_[0] + aq_[1] + aq_[2] + aq_[3];

    const float mean = sum * (1.f / Dn);
    const float var  = sq * (1.f / Dn) - mean * mean;
    const float rstd = rsqrtf(var + 1e-5f);

    float4 g  = *(const float4*)(gamma + t * 4);
    float4 be = *(const float4*)(beta + t * 4);
    float4 o;
    o.x = (v.x - mean) * rstd * g.x + be.x;
    o.y = (v.y - mean) * rstd * g.y + be.y;
    o.z = (v.z - mean) * rstd * g.z + be.z;
    o.w = (v.w - mean) * rstd * g.w + be.w;
    *(float4*)(out + base) = o;
}

extern "C" void kernel_launch(void* const* d_in, const int* in_sizes, int n_in,
                              void* d_out, int out_size, void* d_ws, size_t ws_size,
                              hipStream_t stream) {
    const float* q     = (const float*)d_in[0];
    // d_in[1] (k) and d_in[2] (v) are ignored by the reference (source bug preserved)
    const int*   masks = (const int*)d_in[3];
    const float* pQ    = (const float*)d_in[4];
    const float* pK    = (const float*)d_in[5];
    const float* pV    = (const float*)d_in[6];
    const float* gamma = (const float*)d_in[7];
    const float* beta  = (const float*)d_in[8];
    float* out = (float*)d_out;
    (void)in_sizes; (void)n_in; (void)d_ws; (void)ws_size; (void)out_size;

    dim3 grid(Sn / QT, Bn * Hn);     // 16 x 64
    attn_kernel<<<grid, 256, 0, stream>>>(q, masks, pQ, pK, pV, out);
    ln_kernel<<<Bn * Sn, 256, 0, stream>>>(q, gamma, beta, out);
}

// Round 5
// 290.065 us; speedup vs baseline: 55.4140x; 55.4140x over previous
//
#include <hip/hip_runtime.h>
#include <math.h>

#define Bn 4
#define Sn 2048
#define Dn 1024
#define Hn 16
#define DHn 64
#define QT 128           // q rows per block (4 waves x 32)
#define KT 64            // keys per tile
#define STR 72           // padded ushort stride (144 B rows: b128 reads at bank floor)

typedef __attribute__((ext_vector_type(8))) short short8;
typedef __attribute__((ext_vector_type(4))) float f32x4;

__device__ __forceinline__ ushort f2bf(float f) {
    union { float f; unsigned u; } x; x.f = f;
    unsigned r = x.u + 0x7fffu + ((x.u >> 16) & 1u);   // RNE
    return (ushort)(r >> 16);
}

__global__ __launch_bounds__(256, 2)
void attn_kernel(const float* __restrict__ xin, const int* __restrict__ masks,
                 const float* __restrict__ pQ, const float* __restrict__ pK,
                 const float* __restrict__ pV, float* __restrict__ out)
{
    // Ks: [key][dh] row-major, stride 72
    // Vt: [dh][key] with key-group XOR swizzle: elem (key,dh) at dh*72 + ((key>>3)^(dh>>3))*8 + (key&7)
    // Ps: per-wave: Q staging [q_local][dh], then P [q_local][key]; wave w owns rows w*32..w*32+31
    __shared__ ushort Ks[KT * STR];
    __shared__ ushort Vt[DHn * STR];
    __shared__ ushort Ps[QT * STR];

    const int n  = blockIdx.y;          // b*H + h
    const int b  = n >> 4;
    const int h  = n & 15;
    const int mb = n & 3;               // mask tiling bug preserved: masks[n % B]
    const int q0 = blockIdx.x * QT;

    const int t  = threadIdx.x;
    const int w  = t >> 6;              // wave 0..3
    const int l  = t & 63;
    const int g  = l >> 4;              // lane group 0..3
    const int li = l & 15;

    const float* xb = xin + (size_t)b * Sn * Dn + h * DHn;
    const int dh_t  = l;                // staging: this thread owns dh column dh_t
    const float pk_s = pK[h * DHn + dh_t];
    const float pv_s = pV[h * DHn + dh_t];
    const float pq_s = pQ[h * DHn + dh_t];

    // ---- stage Q (x * proj_Q -> bf16) : wave w rows w*32 .. w*32+31 ----
    #pragma unroll
    for (int i = 0; i < 8; ++i) {
        int qr = w * 32 + i * 4;
        #pragma unroll
        for (int j = 0; j < 4; ++j) {
            float v = xb[(size_t)(q0 + qr + j) * Dn + dh_t];
            Ps[(qr + j) * STR + dh_t] = f2bf(v * pq_s);
        }
    }
    // same-wave LDS write->read: no barrier needed (wave w only touches its rows)
    short8 qf[2][2];                    // [qs][kk]
    #pragma unroll
    for (int qs = 0; qs < 2; ++qs)
        #pragma unroll
        for (int kk = 0; kk < 2; ++kk)
            qf[qs][kk] = *(const short8*)&Ps[(w*32 + qs*16 + li) * STR + kk*32 + g*8];

    f32x4 acc_o[2][4];                  // [qs][dg]; lane reg r: q = qs*16+g*4+r, dh = dg*16+li
    float m_[2][4], l_[2][4];
    #pragma unroll
    for (int qs = 0; qs < 2; ++qs) {
        #pragma unroll
        for (int dg = 0; dg < 4; ++dg) acc_o[qs][dg] = (f32x4){0.f, 0.f, 0.f, 0.f};
        #pragma unroll
        for (int r = 0; r < 4; ++r) { m_[qs][r] = -1e30f; l_[qs][r] = 0.f; }
    }

    const int* mrow = masks + (size_t)mb * Sn * Sn + (size_t)(q0 + w*32) * Sn;

    for (int kt = 0; kt < Sn / KT; ++kt) {
        __syncthreads();                // prior tile's K/V reads complete

        // ---- issue mask loads early (overlap with staging + QK) ----
        int msk[2][4][4];               // [qs][r][kg]
        #pragma unroll
        for (int qs = 0; qs < 2; ++qs)
            #pragma unroll
            for (int r = 0; r < 4; ++r) {
                const int* mp = mrow + (size_t)(qs*16 + g*4 + r) * Sn + kt*KT + li;
                #pragma unroll
                for (int kg = 0; kg < 4; ++kg) msk[qs][r][kg] = mp[kg * 16];
            }

        // ---- stage K,V: wave w keys w*16..w*16+15 (dh-major global reads, coalesced) ----
        #pragma unroll
        for (int i = 0; i < 4; ++i) {
            int kb = w * 16 + i * 4;
            float x0 = xb[(size_t)(kt*KT + kb + 0) * Dn + dh_t];
            float x1 = xb[(size_t)(kt*KT + kb + 1) * Dn + dh_t];
            float x2 = xb[(size_t)(kt*KT + kb + 2) * Dn + dh_t];
            float x3 = xb[(size_t)(kt*KT + kb + 3) * Dn + dh_t];
            Ks[(kb + 0) * STR + dh_t] = f2bf(x0 * pk_s);
            Ks[(kb + 1) * STR + dh_t] = f2bf(x1 * pk_s);
            Ks[(kb + 2) * STR + dh_t] = f2bf(x2 * pk_s);
            Ks[(kb + 3) * STR + dh_t] = f2bf(x3 * pk_s);
            ushort4 vv;
            vv.x = f2bf(x0 * pv_s); vv.y = f2bf(x1 * pv_s);
            vv.z = f2bf(x2 * pv_s); vv.w = f2bf(x3 * pv_s);
            int slotg = (w*2 + (i >> 1)) ^ (dh_t >> 3);
            *(ushort4*)&Vt[dh_t * STR + slotg * 8 + (i & 1) * 4] = vv;
        }
        __syncthreads();

        // ---- QK^T: S[16q x 64key] per qs, via 8 MFMAs each ----
        f32x4 s[2][4];
        #pragma unroll
        for (int qs = 0; qs < 2; ++qs)
            #pragma unroll
            for (int kg = 0; kg < 4; ++kg) s[qs][kg] = (f32x4){0.f, 0.f, 0.f, 0.f};
        #pragma unroll
        for (int kg = 0; kg < 4; ++kg) {
            #pragma unroll
            for (int kk = 0; kk < 2; ++kk) {
                short8 kf = *(const short8*)&Ks[(kg*16 + li) * STR + kk*32 + g*8];
                s[0][kg] = __builtin_amdgcn_mfma_f32_16x16x32_bf16(qf[0][kk], kf, s[0][kg], 0, 0, 0);
                s[1][kg] = __builtin_amdgcn_mfma_f32_16x16x32_bf16(qf[1][kk], kf, s[1][kg], 0, 0, 0);
            }
        }

        // ---- mask + scale + online softmax + P->LDS (bf16) ----
        float al_[2][4];
        #pragma unroll
        for (int qs = 0; qs < 2; ++qs) {
            #pragma unroll
            for (int r = 0; r < 4; ++r) {
                const float sc = 0.03125f;   // 1/sqrt(1024)
                float v0 = msk[qs][r][0] ? -1e-10f : s[qs][0][r] * sc;
                float v1 = msk[qs][r][1] ? -1e-10f : s[qs][1][r] * sc;
                float v2 = msk[qs][r][2] ? -1e-10f : s[qs][2][r] * sc;
                float v3 = msk[qs][r][3] ? -1e-10f : s[qs][3][r] * sc;
                float mx = fmaxf(fmaxf(v0, v1), fmaxf(v2, v3));
                mx = fmaxf(mx, __shfl_xor(mx, 1, 64));
                mx = fmaxf(mx, __shfl_xor(mx, 2, 64));
                mx = fmaxf(mx, __shfl_xor(mx, 4, 64));
                mx = fmaxf(mx, __shfl_xor(mx, 8, 64));
                float mnew = fmaxf(m_[qs][r], mx);
                float al   = __expf(m_[qs][r] - mnew);
                m_[qs][r]  = mnew;
                float e0 = __expf(v0 - mnew);
                float e1 = __expf(v1 - mnew);
                float e2 = __expf(v2 - mnew);
                float e3 = __expf(v3 - mnew);
                float rs = e0 + e1 + e2 + e3;
                rs += __shfl_xor(rs, 1, 64);
                rs += __shfl_xor(rs, 2, 64);
                rs += __shfl_xor(rs, 4, 64);
                rs += __shfl_xor(rs, 8, 64);
                l_[qs][r] = l_[qs][r] * al + rs;
                al_[qs][r] = al;
                int qrow = w*32 + qs*16 + g*4 + r;
                Ps[qrow * STR +  0 + li] = f2bf(e0);
                Ps[qrow * STR + 16 + li] = f2bf(e1);
                Ps[qrow * STR + 32 + li] = f2bf(e2);
                Ps[qrow * STR + 48 + li] = f2bf(e3);
            }
        }
        // rescale O by alpha
        #pragma unroll
        for (int qs = 0; qs < 2; ++qs)
            #pragma unroll
            for (int dg = 0; dg < 4; ++dg)
                #pragma unroll
                for (int r = 0; r < 4; ++r)
                    acc_o[qs][dg][r] *= al_[qs][r];

        // ---- PV: O += P[16q x 32k] * V[32k x 16dh] per (qs, half, dg) ----
        #pragma unroll
        for (int half = 0; half < 2; ++half) {
            short8 vf[4];
            #pragma unroll
            for (int dg = 0; dg < 4; ++dg) {
                int dh = dg*16 + li;
                int slotg = ((half*4 + g) ^ (dh >> 3));
                vf[dg] = *(const short8*)&Vt[dh * STR + slotg * 8];
            }
            #pragma unroll
            for (int qs = 0; qs < 2; ++qs) {
                short8 pf = *(const short8*)&Ps[(w*32 + qs*16 + li) * STR + half*32 + g*8];
                #pragma unroll
                for (int dg = 0; dg < 4; ++dg)
                    acc_o[qs][dg] = __builtin_amdgcn_mfma_f32_16x16x32_bf16(pf, vf[dg], acc_o[qs][dg], 0, 0, 0);
            }
        }
    }

    // ---- epilogue: ctx = O / l -> d_out (fp32; LN kernel finishes) ----
    #pragma unroll
    for (int qs = 0; qs < 2; ++qs) {
        #pragma unroll
        for (int r = 0; r < 4; ++r) {
            float inv = 1.f / l_[qs][r];
            int qg = q0 + w*32 + qs*16 + g*4 + r;
            float* ob = out + ((size_t)b * Sn + qg) * Dn + h * DHn;
            #pragma unroll
            for (int dg = 0; dg < 4; ++dg)
                ob[dg*16 + li] = acc_o[qs][dg][r] * inv;
        }
    }
}

// residual + LayerNorm, in-place on d_out
__global__ __launch_bounds__(256)
void ln_kernel(const float* __restrict__ qin, const float* __restrict__ gamma,
               const float* __restrict__ beta, float* __restrict__ out)
{
    const int row = blockIdx.x;
    const int t   = threadIdx.x;
    const size_t base = (size_t)row * Dn + t * 4;

    float4 c = *(const float4*)(out + base);
    float4 r = *(const float4*)(qin + base);
    float4 v = make_float4(c.x + r.x, c.y + r.y, c.z + r.z, c.w + r.w);

    float sum = v.x + v.y + v.z + v.w;
    float sq  = v.x * v.x + v.y * v.y + v.z * v.z + v.w * v.w;
    #pragma unroll
    for (int off = 32; off >= 1; off >>= 1) {
        sum += __shfl_xor(sum, off, 64);
        sq  += __shfl_xor(sq,  off, 64);
    }
    __shared__ float as_[4], aq_[4];
    const int wid = t >> 6, ln = t & 63;
    if (ln == 0) { as_[wid] = sum; aq_[wid] = sq; }
    __syncthreads();
    sum = as_[0] + as_[1] + as_[2] + as_[3];
    sq  = aq_[0] + aq_[1] + aq_[2] + aq_[3];

    const float mean = sum * (1.f / Dn);
    const float var  = sq * (1.f / Dn) - mean * mean;
    const float rstd = rsqrtf(var + 1e-5f);

    float4 ga = *(const float4*)(gamma + t * 4);
    float4 be = *(const float4*)(beta + t * 4);
    float4 o;
    o.x = (v.x - mean) * rstd * ga.x + be.x;
    o.y = (v.y - mean) * rstd * ga.y + be.y;
    o.z = (v.z - mean) * rstd * ga.z + be.z;
    o.w = (v.w - mean) * rstd * ga.w + be.w;
    *(float4*)(out + base) = o;
}

extern "C" void kernel_launch(void* const* d_in, const int* in_sizes, int n_in,
                              void* d_out, int out_size, void* d_ws, size_t ws_size,
                              hipStream_t stream) {
    const float* q     = (const float*)d_in[0];
    // d_in[1] (k), d_in[2] (v) ignored: reference bug preserved
    const int*   masks = (const int*)d_in[3];
    const float* pQ    = (const float*)d_in[4];
    const float* pK    = (const float*)d_in[5];
    const float* pV    = (const float*)d_in[6];
    const float* gamma = (const float*)d_in[7];
    const float* beta  = (const float*)d_in[8];
    float* out = (float*)d_out;
    (void)in_sizes; (void)n_in; (void)d_ws; (void)ws_size; (void)out_size;

    dim3 grid(Sn / QT, Bn * Hn);     // 16 x 64
    attn_kernel<<<grid, 256, 0, stream>>>(q, masks, pQ, pK, pV, out);
    ln_kernel<<<Bn * Sn, 256, 0, stream>>>(q, gamma, beta, out);
}

// Round 6
// 201.266 us; speedup vs baseline: 79.8624x; 1.4412x over previous
//
#include <hip/hip_runtime.h>
#include <math.h>

#define Bn 4
#define Sn 2048
#define Dn 1024
#define Hn 16
#define DHn 64
#define QT 128           // q rows per block (4 waves x 32)
#define KT 64            // keys per tile
#define STR 72           // padded ushort stride (144 B rows)

typedef __attribute__((ext_vector_type(8))) short short8;
typedef __attribute__((ext_vector_type(4))) float f32x4;

__device__ __forceinline__ ushort f2bf(float f) {
    union { float f; unsigned u; } x; x.f = f;
    unsigned r = x.u + 0x7fffu + ((x.u >> 16) & 1u);   // RNE
    return (ushort)(r >> 16);
}

__device__ __forceinline__ unsigned pack_bf2(float lo, float hi) {
    unsigned r;
    asm("v_cvt_pk_bf16_f32 %0, %1, %2" : "=v"(r) : "v"(lo), "v"(hi));
    return r;
}

// ---------------- prep: x -> bf16 K (row-major) and V (transposed + kappa-permuted) ----------------
// Kbf[n][s][dh] = bf16(x[b][s][h*64+dh] * pK[h*64+dh])
// Vt [n][dh][s0 + kappa(sl)] = bf16(x[b][s0+sl][h*64+dh] * pV[..]),  kappa(16*hi+lo) = 4*lo + hi
__global__ __launch_bounds__(256)
void prep_kv(const float* __restrict__ xin, const float* __restrict__ pK,
             const float* __restrict__ pV, ushort* __restrict__ Kbf,
             ushort* __restrict__ Vtw)
{
    __shared__ ushort Ls[64 * STR];
    const int n = blockIdx.y, b = n >> 4, h = n & 15;
    const int s0 = blockIdx.x * 64;
    const int t = threadIdx.x;
    const int sl = t >> 2, dq = (t & 3) * 16;

    const float* xp = xin + (size_t)b * Sn * Dn + (size_t)(s0 + sl) * Dn + h * DHn + dq;
    const float* pkp = pK + h * DHn + dq;
    const float* pvp = pV + h * DHn + dq;

    float xv[16], pk[16], pv[16];
    #pragma unroll
    for (int j = 0; j < 4; ++j) {
        float4 a = ((const float4*)xp)[j];
        float4 kk = ((const float4*)pkp)[j];
        float4 vv = ((const float4*)pvp)[j];
        xv[4*j+0] = a.x;  xv[4*j+1] = a.y;  xv[4*j+2] = a.z;  xv[4*j+3] = a.w;
        pk[4*j+0] = kk.x; pk[4*j+1] = kk.y; pk[4*j+2] = kk.z; pk[4*j+3] = kk.w;
        pv[4*j+0] = vv.x; pv[4*j+1] = vv.y; pv[4*j+2] = vv.z; pv[4*j+3] = vv.w;
    }

    unsigned kw[8], vw[8];
    #pragma unroll
    for (int j = 0; j < 8; ++j) {
        kw[j] = pack_bf2(xv[2*j] * pk[2*j], xv[2*j+1] * pk[2*j+1]);
        vw[j] = pack_bf2(xv[2*j] * pv[2*j], xv[2*j+1] * pv[2*j+1]);
    }
    ushort* kdst = Kbf + ((size_t)n * Sn + s0 + sl) * DHn + dq;
    *(uint4*)kdst       = make_uint4(kw[0], kw[1], kw[2], kw[3]);
    *(uint4*)(kdst + 8) = make_uint4(kw[4], kw[5], kw[6], kw[7]);

    *(uint4*)&Ls[sl * STR + dq]     = make_uint4(vw[0], vw[1], vw[2], vw[3]);
    *(uint4*)&Ls[sl * STR + dq + 8] = make_uint4(vw[4], vw[5], vw[6], vw[7]);
    __syncthreads();

    const int dh = t >> 2, p4 = t & 3;
    ushort ov[16];
    #pragma unroll
    for (int j = 0; j < 16; ++j) {
        int p  = p4 * 16 + j;                   // kappa slot
        int ss = ((p & 3) << 4) | (p >> 2);     // kappa^-1(p)
        ov[j] = Ls[ss * STR + dh];
    }
    unsigned ow[8];
    #pragma unroll
    for (int j = 0; j < 8; ++j) ow[j] = (unsigned)ov[2*j] | ((unsigned)ov[2*j+1] << 16);
    ushort* vdst = Vtw + ((size_t)n * DHn + dh) * Sn + s0 + p4 * 16;
    *(uint4*)vdst       = make_uint4(ow[0], ow[1], ow[2], ow[3]);
    *(uint4*)(vdst + 8) = make_uint4(ow[4], ow[5], ow[6], ow[7]);
}

// ---------------- fast attention: bf16 K/V from workspace, fixed-max softmax ----------------
__global__ __launch_bounds__(256, 4)
void attn_fast(const float* __restrict__ xin, const int* __restrict__ masks,
               const float* __restrict__ pQ, const ushort* __restrict__ Kbf,
               const ushort* __restrict__ Vtw, float* __restrict__ out)
{
    __shared__ ushort Ks[KT * STR];     // [key][dh]
    __shared__ ushort Vts[KT * STR];    // [dh][kappa-key]
    __shared__ ushort Ps[QT * STR];     // Q staging, then P [q][kappa-key]

    const int n  = blockIdx.y;
    const int b  = n >> 4;
    const int h  = n & 15;
    const int mb = n & 3;               // mask tiling bug preserved: masks[n % B]
    const int q0 = blockIdx.x * QT;

    const int t  = threadIdx.x;
    const int w  = t >> 6;
    const int l  = t & 63;
    const int g  = l >> 4;
    const int li = l & 15;

    // ---- stage Q (fp32 x * proj_Q -> bf16), once per block ----
    const float* xb = xin + (size_t)b * Sn * Dn + h * DHn;
    const float pq_s = pQ[h * DHn + l];
    #pragma unroll
    for (int i = 0; i < 8; ++i) {
        int qr = w * 32 + i * 4;
        #pragma unroll
        for (int j = 0; j < 4; ++j) {
            float v = xb[(size_t)(q0 + qr + j) * Dn + l];
            Ps[(qr + j) * STR + l] = f2bf(v * pq_s);
        }
    }
    short8 qf[2][2];
    #pragma unroll
    for (int qs = 0; qs < 2; ++qs)
        #pragma unroll
        for (int kk = 0; kk < 2; ++kk)
            qf[qs][kk] = *(const short8*)&Ps[(w*32 + qs*16 + li) * STR + kk*32 + g*8];

    f32x4 acc_o[2][4];
    float lsum[2][4];
    #pragma unroll
    for (int qs = 0; qs < 2; ++qs) {
        #pragma unroll
        for (int dg = 0; dg < 4; ++dg) acc_o[qs][dg] = (f32x4){0.f, 0.f, 0.f, 0.f};
        #pragma unroll
        for (int r = 0; r < 4; ++r) lsum[qs][r] = 0.f;
    }

    const int* mrow = masks + (size_t)mb * Sn * Sn + (size_t)(q0 + w*32) * Sn;

    // staging pointers: thread owns (row = w*16 + (l>>2), 16-col chunk part = l&3)
    const int srow = w * 16 + (l >> 2);
    const int part = (l & 3) * 16;
    const ushort* ksrc = Kbf + (size_t)n * Sn * DHn + (size_t)srow * DHn + part;
    const ushort* vsrc = Vtw + (size_t)n * DHn * Sn + (size_t)srow * Sn + part;
    ushort* kdst = &Ks[srow * STR + part];
    ushort* vdst = &Vts[srow * STR + part];

    for (int kt = 0; kt < Sn / KT; ++kt) {
        __syncthreads();
        // ---- stage K,V tiles (bf16, vector) ----
        const ushort* kp = ksrc + (size_t)kt * KT * DHn;
        const ushort* vp = vsrc + kt * KT;
        short8 ka = *(const short8*)kp, kb2 = *(const short8*)(kp + 8);
        short8 va = *(const short8*)vp, vb2 = *(const short8*)(vp + 8);
        *(short8*)kdst       = ka;
        *(short8*)(kdst + 8) = kb2;
        *(short8*)vdst       = va;
        *(short8*)(vdst + 8) = vb2;
        __syncthreads();

        // ---- QK^T ----
        f32x4 s[2][4];
        #pragma unroll
        for (int qs = 0; qs < 2; ++qs)
            #pragma unroll
            for (int kg = 0; kg < 4; ++kg) s[qs][kg] = (f32x4){0.f, 0.f, 0.f, 0.f};
        #pragma unroll
        for (int kg = 0; kg < 4; ++kg) {
            #pragma unroll
            for (int kk = 0; kk < 2; ++kk) {
                short8 kf = *(const short8*)&Ks[(kg*16 + li) * STR + kk*32 + g*8];
                s[0][kg] = __builtin_amdgcn_mfma_f32_16x16x32_bf16(qf[0][kk], kf, s[0][kg], 0, 0, 0);
                s[1][kg] = __builtin_amdgcn_mfma_f32_16x16x32_bf16(qf[1][kk], kf, s[1][kg], 0, 0, 0);
            }
        }

        // ---- mask + exp (fixed max = 0; masked score -1e-10 -> exp == 1.0f) ----
        // e = exp2(score * (1/32) * log2(e)); softmax shift-invariance makes this exact.
        const float C2 = 0.0450842200277800f;   // 0.03125 * log2(e)
        #pragma unroll
        for (int qs = 0; qs < 2; ++qs) {
            #pragma unroll
            for (int r = 0; r < 4; ++r) {
                const int* mp = mrow + (size_t)(qs*16 + g*4 + r) * Sn + kt*KT + li;
                int m0 = mp[0], m1 = mp[16], m2 = mp[32], m3 = mp[48];
                float e0 = exp2f(s[qs][0][r] * C2);
                float e1 = exp2f(s[qs][1][r] * C2);
                float e2 = exp2f(s[qs][2][r] * C2);
                float e3 = exp2f(s[qs][3][r] * C2);
                e0 = m0 ? 1.0f : e0;
                e1 = m1 ? 1.0f : e1;
                e2 = m2 ? 1.0f : e2;
                e3 = m3 ? 1.0f : e3;
                lsum[qs][r] += (e0 + e1) + (e2 + e3);
                uint2 pw;
                pw.x = pack_bf2(e0, e1);
                pw.y = pack_bf2(e2, e3);
                // kappa layout: keys {kg*16+li} -> columns li*4 + kg  (contiguous b64)
                *(uint2*)&Ps[(w*32 + qs*16 + g*4 + r) * STR + li*4] = pw;
            }
        }

        // ---- PV over kappa-ordered keys (V rows pre-permuted in prep) ----
        #pragma unroll
        for (int half = 0; half < 2; ++half) {
            short8 vf[4];
            #pragma unroll
            for (int dg = 0; dg < 4; ++dg)
                vf[dg] = *(const short8*)&Vts[(dg*16 + li) * STR + half*32 + g*8];
            #pragma unroll
            for (int qs = 0; qs < 2; ++qs) {
                short8 pf = *(const short8*)&Ps[(w*32 + qs*16 + li) * STR + half*32 + g*8];
                #pragma unroll
                for (int dg = 0; dg < 4; ++dg)
                    acc_o[qs][dg] = __builtin_amdgcn_mfma_f32_16x16x32_bf16(pf, vf[dg], acc_o[qs][dg], 0, 0, 0);
            }
        }
    }

    // ---- final l reduction across the 16 li lanes ----
    #pragma unroll
    for (int qs = 0; qs < 2; ++qs)
        #pragma unroll
        for (int r = 0; r < 4; ++r) {
            float v = lsum[qs][r];
            v += __shfl_xor(v, 1, 64);
            v += __shfl_xor(v, 2, 64);
            v += __shfl_xor(v, 4, 64);
            v += __shfl_xor(v, 8, 64);
            lsum[qs][r] = v;
        }

    // ---- epilogue: ctx = O / l ----
    #pragma unroll
    for (int qs = 0; qs < 2; ++qs) {
        #pragma unroll
        for (int r = 0; r < 4; ++r) {
            float inv = 1.f / lsum[qs][r];
            int qg = q0 + w*32 + qs*16 + g*4 + r;
            float* ob = out + ((size_t)b * Sn + qg) * Dn + h * DHn;
            #pragma unroll
            for (int dg = 0; dg < 4; ++dg)
                ob[dg*16 + li] = acc_o[qs][dg][r] * inv;
        }
    }
}

// ---------------- fallback (round-5 verified kernel), used if ws too small ----------------
__global__ __launch_bounds__(256, 2)
void attn_kernel(const float* __restrict__ xin, const int* __restrict__ masks,
                 const float* __restrict__ pQ, const float* __restrict__ pK,
                 const float* __restrict__ pV, float* __restrict__ out)
{
    __shared__ ushort Ks[KT * STR];
    __shared__ ushort Vt[DHn * STR];
    __shared__ ushort Ps[QT * STR];

    const int n  = blockIdx.y;
    const int b  = n >> 4;
    const int h  = n & 15;
    const int mb = n & 3;
    const int q0 = blockIdx.x * QT;

    const int t  = threadIdx.x;
    const int w  = t >> 6;
    const int l  = t & 63;
    const int g  = l >> 4;
    const int li = l & 15;

    const float* xb = xin + (size_t)b * Sn * Dn + h * DHn;
    const int dh_t  = l;
    const float pk_s = pK[h * DHn + dh_t];
    const float pv_s = pV[h * DHn + dh_t];
    const float pq_s = pQ[h * DHn + dh_t];

    #pragma unroll
    for (int i = 0; i < 8; ++i) {
        int qr = w * 32 + i * 4;
        #pragma unroll
        for (int j = 0; j < 4; ++j) {
            float v = xb[(size_t)(q0 + qr + j) * Dn + dh_t];
            Ps[(qr + j) * STR + dh_t] = f2bf(v * pq_s);
        }
    }
    short8 qf[2][2];
    #pragma unroll
    for (int qs = 0; qs < 2; ++qs)
        #pragma unroll
        for (int kk = 0; kk < 2; ++kk)
            qf[qs][kk] = *(const short8*)&Ps[(w*32 + qs*16 + li) * STR + kk*32 + g*8];

    f32x4 acc_o[2][4];
    float m_[2][4], l_[2][4];
    #pragma unroll
    for (int qs = 0; qs < 2; ++qs) {
        #pragma unroll
        for (int dg = 0; dg < 4; ++dg) acc_o[qs][dg] = (f32x4){0.f, 0.f, 0.f, 0.f};
        #pragma unroll
        for (int r = 0; r < 4; ++r) { m_[qs][r] = -1e30f; l_[qs][r] = 0.f; }
    }

    const int* mrow = masks + (size_t)mb * Sn * Sn + (size_t)(q0 + w*32) * Sn;

    for (int kt = 0; kt < Sn / KT; ++kt) {
        __syncthreads();
        int msk[2][4][4];
        #pragma unroll
        for (int qs = 0; qs < 2; ++qs)
            #pragma unroll
            for (int r = 0; r < 4; ++r) {
                const int* mp = mrow + (size_t)(qs*16 + g*4 + r) * Sn + kt*KT + li;
                #pragma unroll
                for (int kg = 0; kg < 4; ++kg) msk[qs][r][kg] = mp[kg * 16];
            }
        #pragma unroll
        for (int i = 0; i < 4; ++i) {
            int kb = w * 16 + i * 4;
            float x0 = xb[(size_t)(kt*KT + kb + 0) * Dn + dh_t];
            float x1 = xb[(size_t)(kt*KT + kb + 1) * Dn + dh_t];
            float x2 = xb[(size_t)(kt*KT + kb + 2) * Dn + dh_t];
            float x3 = xb[(size_t)(kt*KT + kb + 3) * Dn + dh_t];
            Ks[(kb + 0) * STR + dh_t] = f2bf(x0 * pk_s);
            Ks[(kb + 1) * STR + dh_t] = f2bf(x1 * pk_s);
            Ks[(kb + 2) * STR + dh_t] = f2bf(x2 * pk_s);
            Ks[(kb + 3) * STR + dh_t] = f2bf(x3 * pk_s);
            ushort4 vv;
            vv.x = f2bf(x0 * pv_s); vv.y = f2bf(x1 * pv_s);
            vv.z = f2bf(x2 * pv_s); vv.w = f2bf(x3 * pv_s);
            int slotg = (w*2 + (i >> 1)) ^ (dh_t >> 3);
            *(ushort4*)&Vt[dh_t * STR + slotg * 8 + (i & 1) * 4] = vv;
        }
        __syncthreads();

        f32x4 s[2][4];
        #pragma unroll
        for (int qs = 0; qs < 2; ++qs)
            #pragma unroll
            for (int kg = 0; kg < 4; ++kg) s[qs][kg] = (f32x4){0.f, 0.f, 0.f, 0.f};
        #pragma unroll
        for (int kg = 0; kg < 4; ++kg) {
            #pragma unroll
            for (int kk = 0; kk < 2; ++kk) {
                short8 kf = *(const short8*)&Ks[(kg*16 + li) * STR + kk*32 + g*8];
                s[0][kg] = __builtin_amdgcn_mfma_f32_16x16x32_bf16(qf[0][kk], kf, s[0][kg], 0, 0, 0);
                s[1][kg] = __builtin_amdgcn_mfma_f32_16x16x32_bf16(qf[1][kk], kf, s[1][kg], 0, 0, 0);
            }
        }

        float al_[2][4];
        #pragma unroll
        for (int qs = 0; qs < 2; ++qs) {
            #pragma unroll
            for (int r = 0; r < 4; ++r) {
                const float sc = 0.03125f;
                float v0 = msk[qs][r][0] ? -1e-10f : s[qs][0][r] * sc;
                float v1 = msk[qs][r][1] ? -1e-10f : s[qs][1][r] * sc;
                float v2 = msk[qs][r][2] ? -1e-10f : s[qs][2][r] * sc;
                float v3 = msk[qs][r][3] ? -1e-10f : s[qs][3][r] * sc;
                float mx = fmaxf(fmaxf(v0, v1), fmaxf(v2, v3));
                mx = fmaxf(mx, __shfl_xor(mx, 1, 64));
                mx = fmaxf(mx, __shfl_xor(mx, 2, 64));
                mx = fmaxf(mx, __shfl_xor(mx, 4, 64));
                mx = fmaxf(mx, __shfl_xor(mx, 8, 64));
                float mnew = fmaxf(m_[qs][r], mx);
                float al   = __expf(m_[qs][r] - mnew);
                m_[qs][r]  = mnew;
                float e0 = __expf(v0 - mnew);
                float e1 = __expf(v1 - mnew);
                float e2 = __expf(v2 - mnew);
                float e3 = __expf(v3 - mnew);
                float rs = e0 + e1 + e2 + e3;
                rs += __shfl_xor(rs, 1, 64);
                rs += __shfl_xor(rs, 2, 64);
                rs += __shfl_xor(rs, 4, 64);
                rs += __shfl_xor(rs, 8, 64);
                l_[qs][r] = l_[qs][r] * al + rs;
                al_[qs][r] = al;
                int qrow = w*32 + qs*16 + g*4 + r;
                Ps[qrow * STR +  0 + li] = f2bf(e0);
                Ps[qrow * STR + 16 + li] = f2bf(e1);
                Ps[qrow * STR + 32 + li] = f2bf(e2);
                Ps[qrow * STR + 48 + li] = f2bf(e3);
            }
        }
        #pragma unroll
        for (int qs = 0; qs < 2; ++qs)
            #pragma unroll
            for (int dg = 0; dg < 4; ++dg)
                #pragma unroll
                for (int r = 0; r < 4; ++r)
                    acc_o[qs][dg][r] *= al_[qs][r];

        #pragma unroll
        for (int half = 0; half < 2; ++half) {
            short8 vf[4];
            #pragma unroll
            for (int dg = 0; dg < 4; ++dg) {
                int dh = dg*16 + li;
                int slotg = ((half*4 + g) ^ (dh >> 3));
                vf[dg] = *(const short8*)&Vt[dh * STR + slotg * 8];
            }
            #pragma unroll
            for (int qs = 0; qs < 2; ++qs) {
                short8 pf = *(const short8*)&Ps[(w*32 + qs*16 + li) * STR + half*32 + g*8];
                #pragma unroll
                for (int dg = 0; dg < 4; ++dg)
                    acc_o[qs][dg] = __builtin_amdgcn_mfma_f32_16x16x32_bf16(pf, vf[dg], acc_o[qs][dg], 0, 0, 0);
            }
        }
    }

    #pragma unroll
    for (int qs = 0; qs < 2; ++qs) {
        #pragma unroll
        for (int r = 0; r < 4; ++r) {
            float inv = 1.f / l_[qs][r];
            int qg = q0 + w*32 + qs*16 + g*4 + r;
            float* ob = out + ((size_t)b * Sn + qg) * Dn + h * DHn;
            #pragma unroll
            for (int dg = 0; dg < 4; ++dg)
                ob[dg*16 + li] = acc_o[qs][dg][r] * inv;
        }
    }
}

// residual + LayerNorm, in-place on d_out
__global__ __launch_bounds__(256)
void ln_kernel(const float* __restrict__ qin, const float* __restrict__ gamma,
               const float* __restrict__ beta, float* __restrict__ out)
{
    const int row = blockIdx.x;
    const int t   = threadIdx.x;
    const size_t base = (size_t)row * Dn + t * 4;

    float4 c = *(const float4*)(out + base);
    float4 r = *(const float4*)(qin + base);
    float4 v = make_float4(c.x + r.x, c.y + r.y, c.z + r.z, c.w + r.w);

    float sum = v.x + v.y + v.z + v.w;
    float sq  = v.x * v.x + v.y * v.y + v.z * v.z + v.w * v.w;
    #pragma unroll
    for (int off = 32; off >= 1; off >>= 1) {
        sum += __shfl_xor(sum, off, 64);
        sq  += __shfl_xor(sq,  off, 64);
    }
    __shared__ float as_[4], aq_[4];
    const int wid = t >> 6, ln = t & 63;
    if (ln == 0) { as_[wid] = sum; aq_[wid] = sq; }
    __syncthreads();
    sum = as_[0] + as_[1] + as_[2] + as_[3];
    sq  = aq_[0] + aq_[1] + aq_[2] + aq_[3];

    const float mean = sum * (1.f / Dn);
    const float var  = sq * (1.f / Dn) - mean * mean;
    const float rstd = rsqrtf(var + 1e-5f);

    float4 ga = *(const float4*)(gamma + t * 4);
    float4 be = *(const float4*)(beta + t * 4);
    float4 o;
    o.x = (v.x - mean) * rstd * ga.x + be.x;
    o.y = (v.y - mean) * rstd * ga.y + be.y;
    o.z = (v.z - mean) * rstd * ga.z + be.z;
    o.w = (v.w - mean) * rstd * ga.w + be.w;
    *(float4*)(out + base) = o;
}

extern "C" void kernel_launch(void* const* d_in, const int* in_sizes, int n_in,
                              void* d_out, int out_size, void* d_ws, size_t ws_size,
                              hipStream_t stream) {
    const float* q     = (const float*)d_in[0];
    // d_in[1] (k), d_in[2] (v) ignored: reference bug preserved
    const int*   masks = (const int*)d_in[3];
    const float* pQ    = (const float*)d_in[4];
    const float* pK    = (const float*)d_in[5];
    const float* pV    = (const float*)d_in[6];
    const float* gamma = (const float*)d_in[7];
    const float* beta  = (const float*)d_in[8];
    float* out = (float*)d_out;
    (void)in_sizes; (void)n_in; (void)out_size;

    const size_t elems = (size_t)Bn * Hn * Sn * DHn;        // 8,388,608 per array
    const size_t need  = elems * 2 * sizeof(ushort);        // 32 MiB

    dim3 grid(Sn / QT, Bn * Hn);
    if (ws_size >= need) {
        ushort* Kbf = (ushort*)d_ws;
        ushort* Vtw = Kbf + elems;
        prep_kv<<<dim3(Sn / 64, Bn * Hn), 256, 0, stream>>>(q, pK, pV, Kbf, Vtw);
        attn_fast<<<grid, 256, 0, stream>>>(q, masks, pQ, Kbf, Vtw, out);
    } else {
        attn_kernel<<<grid, 256, 0, stream>>>(q, masks, pQ, pK, pV, out);
    }
    ln_kernel<<<Bn * Sn, 256, 0, stream>>>(q, gamma, beta, out);
}

// Round 7
// 176.542 us; speedup vs baseline: 91.0471x; 1.1400x over previous
//
#include <hip/hip_runtime.h>
#include <math.h>

#define Bn 4
#define Sn 2048
#define Dn 1024
#define Hn 16
#define DHn 64
#define QT 128           // q rows per block (4 waves x 32)
#define KT 64            // keys per tile
#define STR 72           // padded ushort stride (144 B rows)

typedef __attribute__((ext_vector_type(8))) short short8;
typedef __attribute__((ext_vector_type(4))) float f32x4;

__device__ __forceinline__ ushort f2bf(float f) {
    union { float f; unsigned u; } x; x.f = f;
    unsigned r = x.u + 0x7fffu + ((x.u >> 16) & 1u);   // RNE
    return (ushort)(r >> 16);
}

__device__ __forceinline__ unsigned pack_bf2(float lo, float hi) {
    unsigned r;
    asm("v_cvt_pk_bf16_f32 %0, %1, %2" : "=v"(r) : "v"(lo), "v"(hi));
    return r;
}

// ---------------- prep: x -> bf16 K (row-major) and V (transposed + psi-permuted) ----------------
// Kbf[n][s][dh]            = bf16(x[b][s][h*64+dh] * pK[..])
// Vtw[n][dh][s0 + p]       = bf16(x[b][s0 + psi_inv(p)][h*64+dh] * pV[..])
//   psi_inv(p) = (p&32) | ((p&4)<<2) | ((p&24)>>1) | (p&3)
__global__ __launch_bounds__(256)
void prep_kv(const float* __restrict__ xin, const float* __restrict__ pK,
             const float* __restrict__ pV, ushort* __restrict__ Kbf,
             ushort* __restrict__ Vtw)
{
    __shared__ ushort Ls[64 * STR];
    const int n = blockIdx.y, b = n >> 4, h = n & 15;
    const int s0 = blockIdx.x * 64;
    const int t = threadIdx.x;
    const int sl = t >> 2, dq = (t & 3) * 16;

    const float* xp = xin + (size_t)b * Sn * Dn + (size_t)(s0 + sl) * Dn + h * DHn + dq;
    const float* pkp = pK + h * DHn + dq;
    const float* pvp = pV + h * DHn + dq;

    float xv[16], pk[16], pv[16];
    #pragma unroll
    for (int j = 0; j < 4; ++j) {
        float4 a = ((const float4*)xp)[j];
        float4 kk = ((const float4*)pkp)[j];
        float4 vv = ((const float4*)pvp)[j];
        xv[4*j+0] = a.x;  xv[4*j+1] = a.y;  xv[4*j+2] = a.z;  xv[4*j+3] = a.w;
        pk[4*j+0] = kk.x; pk[4*j+1] = kk.y; pk[4*j+2] = kk.z; pk[4*j+3] = kk.w;
        pv[4*j+0] = vv.x; pv[4*j+1] = vv.y; pv[4*j+2] = vv.z; pv[4*j+3] = vv.w;
    }

    unsigned kw[8], vw[8];
    #pragma unroll
    for (int j = 0; j < 8; ++j) {
        kw[j] = pack_bf2(xv[2*j] * pk[2*j], xv[2*j+1] * pk[2*j+1]);
        vw[j] = pack_bf2(xv[2*j] * pv[2*j], xv[2*j+1] * pv[2*j+1]);
    }
    ushort* kdst = Kbf + ((size_t)n * Sn + s0 + sl) * DHn + dq;
    *(uint4*)kdst       = make_uint4(kw[0], kw[1], kw[2], kw[3]);
    *(uint4*)(kdst + 8) = make_uint4(kw[4], kw[5], kw[6], kw[7]);

    *(uint4*)&Ls[sl * STR + dq]     = make_uint4(vw[0], vw[1], vw[2], vw[3]);
    *(uint4*)&Ls[sl * STR + dq + 8] = make_uint4(vw[4], vw[5], vw[6], vw[7]);
    __syncthreads();

    const int dh = t >> 2, p4 = t & 3;
    ushort ov[16];
    #pragma unroll
    for (int j = 0; j < 16; ++j) {
        int p  = p4 * 16 + j;
        int ss = (p & 32) | ((p & 4) << 2) | ((p & 24) >> 1) | (p & 3);   // psi^-1
        ov[j] = Ls[ss * STR + dh];
    }
    unsigned ow[8];
    #pragma unroll
    for (int j = 0; j < 8; ++j) ow[j] = (unsigned)ov[2*j] | ((unsigned)ov[2*j+1] << 16);
    ushort* vdst = Vtw + ((size_t)n * DHn + dh) * Sn + s0 + p4 * 16;
    *(uint4*)vdst       = make_uint4(ow[0], ow[1], ow[2], ow[3]);
    *(uint4*)(vdst + 8) = make_uint4(ow[4], ow[5], ow[6], ow[7]);
}

// ---------------- attention: swapped-QK, in-register P, no P LDS round-trip ----------------
__global__ __launch_bounds__(256, 4)
void attn_fast2(const float* __restrict__ xin, const int* __restrict__ masks,
                const float* __restrict__ pQ, const ushort* __restrict__ Kbf,
                const ushort* __restrict__ Vtw, float* __restrict__ out)
{
    __shared__ ushort Ks[KT * STR];     // [key][dh]
    __shared__ ushort Vts[DHn * STR];   // [dh][psi-key]

    const int n  = blockIdx.y;
    const int b  = n >> 4;
    const int h  = n & 15;
    const int mb = n & 3;               // mask tiling bug preserved: masks[n % B]
    const int q0 = blockIdx.x * QT;

    const int t  = threadIdx.x;
    const int w  = t >> 6;
    const int l  = t & 63;
    const int G  = l >> 4;
    const int li = l & 15;

    // ---- stage this wave's 32 Q rows (x * pQ * C2 -> bf16) into scratch LDS ----
    const float C2 = 0.0450842200277800f;   // (1/32) * log2(e), folded into Q
    const float* xb = xin + (size_t)b * Sn * Dn + h * DHn;
    const float pq_s = pQ[h * DHn + l] * C2;
    ushort* qstage = ((w < 2) ? Ks : Vts) + (w & 1) * (32 * STR);
    #pragma unroll
    for (int i = 0; i < 8; ++i) {
        #pragma unroll
        for (int j = 0; j < 4; ++j) {
            int qr = i * 4 + j;
            float v = xb[(size_t)(q0 + w * 32 + qr) * Dn + l];
            qstage[qr * STR + l] = f2bf(v * pq_s);
        }
    }
    // same-wave write->read, no barrier needed
    short8 qf[2][2];                    // [qs][kk]: lane li <-> q row, elems dh kk*32+G*8..
    #pragma unroll
    for (int qs = 0; qs < 2; ++qs)
        #pragma unroll
        for (int kk = 0; kk < 2; ++kk)
            qf[qs][kk] = *(const short8*)&qstage[(qs*16 + li) * STR + kk*32 + G*8];

    f32x4 acc_o[2][4];                  // [qs][dg]: row r -> q = qs*16+4G+r, col li -> dh dg*16+li
    float lsum[2];
    #pragma unroll
    for (int qs = 0; qs < 2; ++qs) {
        #pragma unroll
        for (int dg = 0; dg < 4; ++dg) acc_o[qs][dg] = (f32x4){0.f, 0.f, 0.f, 0.f};
        lsum[qs] = 0.f;
    }

    const int* mq = masks + (size_t)mb * Sn * Sn + (size_t)(q0 + w*32 + li) * Sn;

    const int srow = w * 16 + (l >> 2);
    const int part = (l & 3) * 16;
    const ushort* ksrc = Kbf + (size_t)n * Sn * DHn + (size_t)srow * DHn + part;
    const ushort* vsrc = Vtw + (size_t)n * DHn * Sn + (size_t)srow * Sn + part;
    ushort* kdst = &Ks[srow * STR + part];
    ushort* vdst = &Vts[srow * STR + part];

    for (int kt = 0; kt < Sn / KT; ++kt) {
        __syncthreads();
        // ---- stage K,V tiles from bf16 workspace ----
        const ushort* kp = ksrc + (size_t)kt * KT * DHn;
        const ushort* vp = vsrc + kt * KT;
        short8 k0 = *(const short8*)kp, k1 = *(const short8*)(kp + 8);
        short8 v0 = *(const short8*)vp, v1 = *(const short8*)(vp + 8);
        *(short8*)kdst       = k0;
        *(short8*)(kdst + 8) = k1;
        *(short8*)vdst       = v0;
        *(short8*)(vdst + 8) = v1;
        __syncthreads();

        // ---- swapped QK^T: St = mfma(K, Q); lane holds S[key 16kg+4G+r][q=qs*16+li] ----
        f32x4 s[2][4];
        #pragma unroll
        for (int qs = 0; qs < 2; ++qs)
            #pragma unroll
            for (int kg = 0; kg < 4; ++kg) s[qs][kg] = (f32x4){0.f, 0.f, 0.f, 0.f};
        __builtin_amdgcn_s_setprio(1);
        #pragma unroll
        for (int kg = 0; kg < 4; ++kg) {
            #pragma unroll
            for (int kk = 0; kk < 2; ++kk) {
                short8 kf = *(const short8*)&Ks[(kg*16 + li) * STR + kk*32 + G*8];
                s[0][kg] = __builtin_amdgcn_mfma_f32_16x16x32_bf16(kf, qf[0][kk], s[0][kg], 0, 0, 0);
                s[1][kg] = __builtin_amdgcn_mfma_f32_16x16x32_bf16(kf, qf[1][kk], s[1][kg], 0, 0, 0);
            }
        }
        __builtin_amdgcn_s_setprio(0);

        // ---- mask + exp + in-register P pack (no LDS round-trip) ----
        short8 pf[2][2];                // [qs][h]: A-operand for PV
        #pragma unroll
        for (int qs = 0; qs < 2; ++qs) {
            int4 mv[4];
            #pragma unroll
            for (int kg = 0; kg < 4; ++kg)
                mv[kg] = *(const int4*)(mq + (size_t)qs*16*Sn + kt*KT + kg*16 + G*4);
            float ev[16];
            #pragma unroll
            for (int kg = 0; kg < 4; ++kg) {
                int ma[4] = {mv[kg].x, mv[kg].y, mv[kg].z, mv[kg].w};
                #pragma unroll
                for (int r = 0; r < 4; ++r) {
                    float tt = ma[r] ? 0.f : s[qs][kg][r];   // masked -> exp2(0) == 1.0
                    ev[kg*4 + r] = exp2f(tt);
                }
            }
            lsum[qs] += (((ev[0]+ev[1])+(ev[2]+ev[3])) + ((ev[4]+ev[5])+(ev[6]+ev[7])))
                      + (((ev[8]+ev[9])+(ev[10]+ev[11])) + ((ev[12]+ev[13])+(ev[14]+ev[15])));
            #pragma unroll
            for (int hh = 0; hh < 2; ++hh) {
                union { unsigned u[4]; short8 v; } pu;
                pu.u[0] = pack_bf2(ev[hh*8+0], ev[hh*8+1]);
                pu.u[1] = pack_bf2(ev[hh*8+2], ev[hh*8+3]);
                pu.u[2] = pack_bf2(ev[hh*8+4], ev[hh*8+5]);
                pu.u[3] = pack_bf2(ev[hh*8+6], ev[hh*8+7]);
                pf[qs][hh] = pu.v;
            }
        }

        // ---- PV: acc += P * V (psi-ordered V rows match P element order) ----
        #pragma unroll
        for (int hh = 0; hh < 2; ++hh) {
            short8 vf[4];
            #pragma unroll
            for (int dg = 0; dg < 4; ++dg)
                vf[dg] = *(const short8*)&Vts[(dg*16 + li) * STR + hh*32 + G*8];
            __builtin_amdgcn_s_setprio(1);
            #pragma unroll
            for (int qs = 0; qs < 2; ++qs)
                #pragma unroll
                for (int dg = 0; dg < 4; ++dg)
                    acc_o[qs][dg] = __builtin_amdgcn_mfma_f32_16x16x32_bf16(pf[qs][hh], vf[dg], acc_o[qs][dg], 0, 0, 0);
            __builtin_amdgcn_s_setprio(0);
        }
    }

    // ---- l reduction: partial per (G, li) covers keys {16kg+4G+r}; reduce across G ----
    #pragma unroll
    for (int qs = 0; qs < 2; ++qs) {
        float v = lsum[qs];
        v += __shfl_xor(v, 16, 64);
        v += __shfl_xor(v, 32, 64);
        lsum[qs] = v;                   // full row sum for q = qs*16+li, replicated over G
    }

    // ---- epilogue: ctx = O / l ----
    #pragma unroll
    for (int qs = 0; qs < 2; ++qs) {
        #pragma unroll
        for (int r = 0; r < 4; ++r) {
            float lv = __shfl(lsum[qs], (l & 48) | (G * 4 + r), 64);
            float inv = 1.f / lv;
            int qg = q0 + w*32 + qs*16 + G*4 + r;
            float* ob = out + ((size_t)b * Sn + qg) * Dn + h * DHn;
            #pragma unroll
            for (int dg = 0; dg < 4; ++dg)
                ob[dg*16 + li] = acc_o[qs][dg][r] * inv;
        }
    }
}

// ---------------- fallback (round-5 verified kernel), used if ws too small ----------------
__global__ __launch_bounds__(256, 2)
void attn_kernel(const float* __restrict__ xin, const int* __restrict__ masks,
                 const float* __restrict__ pQ, const float* __restrict__ pK,
                 const float* __restrict__ pV, float* __restrict__ out)
{
    __shared__ ushort Ks[KT * STR];
    __shared__ ushort Vt[DHn * STR];
    __shared__ ushort Ps[QT * STR];

    const int n  = blockIdx.y;
    const int b  = n >> 4;
    const int h  = n & 15;
    const int mb = n & 3;
    const int q0 = blockIdx.x * QT;

    const int t  = threadIdx.x;
    const int w  = t >> 6;
    const int l  = t & 63;
    const int g  = l >> 4;
    const int li = l & 15;

    const float* xb = xin + (size_t)b * Sn * Dn + h * DHn;
    const int dh_t  = l;
    const float pk_s = pK[h * DHn + dh_t];
    const float pv_s = pV[h * DHn + dh_t];
    const float pq_s = pQ[h * DHn + dh_t];

    #pragma unroll
    for (int i = 0; i < 8; ++i) {
        int qr = w * 32 + i * 4;
        #pragma unroll
        for (int j = 0; j < 4; ++j) {
            float v = xb[(size_t)(q0 + qr + j) * Dn + dh_t];
            Ps[(qr + j) * STR + dh_t] = f2bf(v * pq_s);
        }
    }
    short8 qf[2][2];
    #pragma unroll
    for (int qs = 0; qs < 2; ++qs)
        #pragma unroll
        for (int kk = 0; kk < 2; ++kk)
            qf[qs][kk] = *(const short8*)&Ps[(w*32 + qs*16 + li) * STR + kk*32 + g*8];

    f32x4 acc_o[2][4];
    float m_[2][4], l_[2][4];
    #pragma unroll
    for (int qs = 0; qs < 2; ++qs) {
        #pragma unroll
        for (int dg = 0; dg < 4; ++dg) acc_o[qs][dg] = (f32x4){0.f, 0.f, 0.f, 0.f};
        #pragma unroll
        for (int r = 0; r < 4; ++r) { m_[qs][r] = -1e30f; l_[qs][r] = 0.f; }
    }

    const int* mrow = masks + (size_t)mb * Sn * Sn + (size_t)(q0 + w*32) * Sn;

    for (int kt = 0; kt < Sn / KT; ++kt) {
        __syncthreads();
        int msk[2][4][4];
        #pragma unroll
        for (int qs = 0; qs < 2; ++qs)
            #pragma unroll
            for (int r = 0; r < 4; ++r) {
                const int* mp = mrow + (size_t)(qs*16 + g*4 + r) * Sn + kt*KT + li;
                #pragma unroll
                for (int kg = 0; kg < 4; ++kg) msk[qs][r][kg] = mp[kg * 16];
            }
        #pragma unroll
        for (int i = 0; i < 4; ++i) {
            int kb = w * 16 + i * 4;
            float x0 = xb[(size_t)(kt*KT + kb + 0) * Dn + dh_t];
            float x1 = xb[(size_t)(kt*KT + kb + 1) * Dn + dh_t];
            float x2 = xb[(size_t)(kt*KT + kb + 2) * Dn + dh_t];
            float x3 = xb[(size_t)(kt*KT + kb + 3) * Dn + dh_t];
            Ks[(kb + 0) * STR + dh_t] = f2bf(x0 * pk_s);
            Ks[(kb + 1) * STR + dh_t] = f2bf(x1 * pk_s);
            Ks[(kb + 2) * STR + dh_t] = f2bf(x2 * pk_s);
            Ks[(kb + 3) * STR + dh_t] = f2bf(x3 * pk_s);
            ushort4 vv;
            vv.x = f2bf(x0 * pv_s); vv.y = f2bf(x1 * pv_s);
            vv.z = f2bf(x2 * pv_s); vv.w = f2bf(x3 * pv_s);
            int slotg = (w*2 + (i >> 1)) ^ (dh_t >> 3);
            *(ushort4*)&Vt[dh_t * STR + slotg * 8 + (i & 1) * 4] = vv;
        }
        __syncthreads();

        f32x4 s[2][4];
        #pragma unroll
        for (int qs = 0; qs < 2; ++qs)
            #pragma unroll
            for (int kg = 0; kg < 4; ++kg) s[qs][kg] = (f32x4){0.f, 0.f, 0.f, 0.f};
        #pragma unroll
        for (int kg = 0; kg < 4; ++kg) {
            #pragma unroll
            for (int kk = 0; kk < 2; ++kk) {
                short8 kf = *(const short8*)&Ks[(kg*16 + li) * STR + kk*32 + g*8];
                s[0][kg] = __builtin_amdgcn_mfma_f32_16x16x32_bf16(qf[0][kk], kf, s[0][kg], 0, 0, 0);
                s[1][kg] = __builtin_amdgcn_mfma_f32_16x16x32_bf16(qf[1][kk], kf, s[1][kg], 0, 0, 0);
            }
        }

        float al_[2][4];
        #pragma unroll
        for (int qs = 0; qs < 2; ++qs) {
            #pragma unroll
            for (int r = 0; r < 4; ++r) {
                const float sc = 0.03125f;
                float v0 = msk[qs][r][0] ? -1e-10f : s[qs][0][r] * sc;
                float v1 = msk[qs][r][1] ? -1e-10f : s[qs][1][r] * sc;
                float v2 = msk[qs][r][2] ? -1e-10f : s[qs][2][r] * sc;
                float v3 = msk[qs][r][3] ? -1e-10f : s[qs][3][r] * sc;
                float mx = fmaxf(fmaxf(v0, v1), fmaxf(v2, v3));
                mx = fmaxf(mx, __shfl_xor(mx, 1, 64));
                mx = fmaxf(mx, __shfl_xor(mx, 2, 64));
                mx = fmaxf(mx, __shfl_xor(mx, 4, 64));
                mx = fmaxf(mx, __shfl_xor(mx, 8, 64));
                float mnew = fmaxf(m_[qs][r], mx);
                float al   = __expf(m_[qs][r] - mnew);
                m_[qs][r]  = mnew;
                float e0 = __expf(v0 - mnew);
                float e1 = __expf(v1 - mnew);
                float e2 = __expf(v2 - mnew);
                float e3 = __expf(v3 - mnew);
                float rs = e0 + e1 + e2 + e3;
                rs += __shfl_xor(rs, 1, 64);
                rs += __shfl_xor(rs, 2, 64);
                rs += __shfl_xor(rs, 4, 64);
                rs += __shfl_xor(rs, 8, 64);
                l_[qs][r] = l_[qs][r] * al + rs;
                al_[qs][r] = al;
                int qrow = w*32 + qs*16 + g*4 + r;
                Ps[qrow * STR +  0 + li] = f2bf(e0);
                Ps[qrow * STR + 16 + li] = f2bf(e1);
                Ps[qrow * STR + 32 + li] = f2bf(e2);
                Ps[qrow * STR + 48 + li] = f2bf(e3);
            }
        }
        #pragma unroll
        for (int qs = 0; qs < 2; ++qs)
            #pragma unroll
            for (int dg = 0; dg < 4; ++dg)
                #pragma unroll
                for (int r = 0; r < 4; ++r)
                    acc_o[qs][dg][r] *= al_[qs][r];

        #pragma unroll
        for (int half = 0; half < 2; ++half) {
            short8 vf[4];
            #pragma unroll
            for (int dg = 0; dg < 4; ++dg) {
                int dh = dg*16 + li;
                int slotg = ((half*4 + g) ^ (dh >> 3));
                vf[dg] = *(const short8*)&Vt[dh * STR + slotg * 8];
            }
            #pragma unroll
            for (int qs = 0; qs < 2; ++qs) {
                short8 pf = *(const short8*)&Ps[(w*32 + qs*16 + li) * STR + half*32 + g*8];
                #pragma unroll
                for (int dg = 0; dg < 4; ++dg)
                    acc_o[qs][dg] = __builtin_amdgcn_mfma_f32_16x16x32_bf16(pf, vf[dg], acc_o[qs][dg], 0, 0, 0);
            }
        }
    }

    #pragma unroll
    for (int qs = 0; qs < 2; ++qs) {
        #pragma unroll
        for (int r = 0; r < 4; ++r) {
            float inv = 1.f / l_[qs][r];
            int qg = q0 + w*32 + qs*16 + g*4 + r;
            float* ob = out + ((size_t)b * Sn + qg) * Dn + h * DHn;
            #pragma unroll
            for (int dg = 0; dg < 4; ++dg)
                ob[dg*16 + li] = acc_o[qs][dg][r] * inv;
        }
    }
}

// residual + LayerNorm, in-place on d_out
__global__ __launch_bounds__(256)
void ln_kernel(const float* __restrict__ qin, const float* __restrict__ gamma,
               const float* __restrict__ beta, float* __restrict__ out)
{
    const int row = blockIdx.x;
    const int t   = threadIdx.x;
    const size_t base = (size_t)row * Dn + t * 4;

    float4 c = *(const float4*)(out + base);
    float4 r = *(const float4*)(qin + base);
    float4 v = make_float4(c.x + r.x, c.y + r.y, c.z + r.z, c.w + r.w);

    float sum = v.x + v.y + v.z + v.w;
    float sq  = v.x * v.x + v.y * v.y + v.z * v.z + v.w * v.w;
    #pragma unroll
    for (int off = 32; off >= 1; off >>= 1) {
        sum += __shfl_xor(sum, off, 64);
        sq  += __shfl_xor(sq,  off, 64);
    }
    __shared__ float as_[4], aq_[4];
    const int wid = t >> 6, ln = t & 63;
    if (ln == 0) { as_[wid] = sum; aq_[wid] = sq; }
    __syncthreads();
    sum = as_[0] + as_[1] + as_[2] + as_[3];
    sq  = aq_[0] + aq_[1] + aq_[2] + aq_[3];

    const float mean = sum * (1.f / Dn);
    const float var  = sq * (1.f / Dn) - mean * mean;
    const float rstd = rsqrtf(var + 1e-5f);

    float4 ga = *(const float4*)(gamma + t * 4);
    float4 be = *(const float4*)(beta + t * 4);
    float4 o;
    o.x = (v.x - mean) * rstd * ga.x + be.x;
    o.y = (v.y - mean) * rstd * ga.y + be.y;
    o.z = (v.z - mean) * rstd * ga.z + be.z;
    o.w = (v.w - mean) * rstd * ga.w + be.w;
    *(float4*)(out + base) = o;
}

extern "C" void kernel_launch(void* const* d_in, const int* in_sizes, int n_in,
                              void* d_out, int out_size, void* d_ws, size_t ws_size,
                              hipStream_t stream) {
    const float* q     = (const float*)d_in[0];
    // d_in[1] (k), d_in[2] (v) ignored: reference bug preserved
    const int*   masks = (const int*)d_in[3];
    const float* pQ    = (const float*)d_in[4];
    const float* pK    = (const float*)d_in[5];
    const float* pV    = (const float*)d_in[6];
    const float* gamma = (const float*)d_in[7];
    const float* beta  = (const float*)d_in[8];
    float* out = (float*)d_out;
    (void)in_sizes; (void)n_in; (void)out_size;

    const size_t elems = (size_t)Bn * Hn * Sn * DHn;        // 8,388,608 per array
    const size_t need  = elems * 2 * sizeof(ushort);        // 32 MiB

    dim3 grid(Sn / QT, Bn * Hn);
    if (ws_size >= need) {
        ushort* Kbf = (ushort*)d_ws;
        ushort* Vtw = Kbf + elems;
        prep_kv<<<dim3(Sn / 64, Bn * Hn), 256, 0, stream>>>(q, pK, pV, Kbf, Vtw);
        attn_fast2<<<grid, 256, 0, stream>>>(q, masks, pQ, Kbf, Vtw, out);
    } else {
        attn_kernel<<<grid, 256, 0, stream>>>(q, masks, pQ, pK, pV, out);
    }
    ln_kernel<<<Bn * Sn, 256, 0, stream>>>(q, gamma, beta, out);
}